// Round 15
// baseline (89.865 us; speedup 1.0000x reference)
//
#include <hip/hip_runtime.h>
#include <cstdint>
#include <cstddef>

#define NEG_SLOPE 0.2f

typedef __attribute__((ext_vector_type(8))) short bf16x8;
typedef __attribute__((ext_vector_type(8))) unsigned short u16x8;
typedef __attribute__((ext_vector_type(4))) unsigned short u16x4;
typedef __attribute__((ext_vector_type(4))) float f32x4;
typedef __attribute__((ext_vector_type(2))) float f32x2;

__device__ __forceinline__ float leaky_f(float x) { return x >= 0.f ? x : NEG_SLOPE * x; }

__device__ __forceinline__ unsigned short f2bf(float f) {
    union { float f; uint32_t u; } v; v.f = f;
    return (unsigned short)((v.u + 0x7fffu + ((v.u >> 16) & 1u)) >> 16);
}
__device__ __forceinline__ float bf2f(unsigned short u) {
    union { uint32_t u; float f; } v; v.u = ((uint32_t)u) << 16; return v.f;
}
__device__ __forceinline__ float bfhi(uint32_t w) {
    union { uint32_t u; float f; } v; v.u = w & 0xffff0000u; return v.f;
}
__device__ __forceinline__ float bflo(uint32_t w) {
    union { uint32_t u; float f; } v; v.u = w << 16; return v.f;
}
__device__ __forceinline__ u16x8 cvt8(float4 a, float4 b) {
    u16x8 o;
    o[0] = f2bf(a.x); o[1] = f2bf(a.y); o[2] = f2bf(a.z); o[3] = f2bf(a.w);
    o[4] = f2bf(b.x); o[5] = f2bf(b.y); o[6] = f2bf(b.z); o[7] = f2bf(b.w);
    return o;
}

#if __has_builtin(__builtin_elementwise_fma)
__device__ __forceinline__ f32x2 fma2(f32x2 a, f32x2 b, f32x2 c) {
    return __builtin_elementwise_fma(a, b, c);
}
#else
__device__ __forceinline__ f32x2 fma2(f32x2 a, f32x2 b, f32x2 c) {
    f32x2 r; r[0] = fmaf(a[0], b[0], c[0]); r[1] = fmaf(a[1], b[1], c[1]); return r;
}
#endif

// ==================== pack: weights -> fragment-ready bf16; x_node -> bf16; cn2 ====================
__global__ __launch_bounds__(256)
void pack_kernel(const float* __restrict__ x_node, const float* __restrict__ W1,
                 const float* __restrict__ W2, const float* __restrict__ W21,
                 const float* __restrict__ cent,
                 unsigned short* __restrict__ xb, unsigned short* __restrict__ pw1,
                 unsigned short* __restrict__ pw2, unsigned short* __restrict__ pw3,
                 float* __restrict__ cn2g, int N)
{
    const int bid = blockIdx.x, tid = threadIdx.x;
    if (bid < 36) {                       // 144 weight fragments, 4 per block
        const int sub = tid >> 6, lane = tid & 63, g = bid * 4 + sub;
        const int l15 = lane & 15, l4 = lane >> 4;
        const float* src; unsigned short* dst;
        if (g < 64) {        // W1: 8 steps x 8 frags, K=256
            int step = g >> 3, f = g & 7;
            src = W1 + (size_t)(f * 16 + l15) * 256 + step * 32 + l4 * 8;
            dst = pw1 + ((size_t)(step * 8 + f) * 64 + lane) * 8;
        } else if (g < 96) { // W2: 4 steps x 8 frags, K=128
            int gg = g - 64, step = gg >> 3, f = gg & 7;
            src = W2 + (size_t)(f * 16 + l15) * 128 + step * 32 + l4 * 8;
            dst = pw2 + ((size_t)(step * 8 + f) * 64 + lane) * 8;
        } else {             // [W21;cent]: 4 steps x 12 frags, K=128
            int gg = g - 96, step = gg / 12, f = gg % 12;
            int brow = f * 16 + l15;
            const float* base = (brow < 128) ? (W21 + (size_t)brow * 128)
                                             : (cent + (size_t)(brow - 128) * 128);
            src = base + step * 32 + l4 * 8;
            dst = pw3 + ((size_t)(step * 12 + f) * 64 + lane) * 8;
        }
        float4 a = *reinterpret_cast<const float4*>(src);
        float4 b = *reinterpret_cast<const float4*>(src + 4);
        *reinterpret_cast<u16x8*>(dst) = cvt8(a, b);
    } else if (bid == 36) {               // cn2
        int r = tid >> 2, c0 = (tid & 3) * 32;
        const float* cr = cent + (size_t)r * 128 + c0;
        float s = 0.f;
#pragma unroll
        for (int q = 0; q < 8; q++) {
            float4 v = *reinterpret_cast<const float4*>(cr + q * 4);
            s += v.x * v.x + v.y * v.y + v.z * v.z + v.w * v.w;
        }
        s += __shfl_xor(s, 1); s += __shfl_xor(s, 2);
        if ((tid & 3) == 0) cn2g[r] = s;
    } else {                              // x_node -> bf16, 4096 elems/block
        size_t base = (size_t)(bid - 37) * 4096 + (size_t)tid * 16;
        float4 v0 = *reinterpret_cast<const float4*>(x_node + base);
        float4 v1 = *reinterpret_cast<const float4*>(x_node + base + 4);
        float4 v2 = *reinterpret_cast<const float4*>(x_node + base + 8);
        float4 v3 = *reinterpret_cast<const float4*>(x_node + base + 12);
        *reinterpret_cast<u16x8*>(xb + base)     = cvt8(v0, v1);
        *reinterpret_cast<u16x8*>(xb + base + 8) = cvt8(v2, v3);
    }
}

// ==================== fused GEMM chain: 16 rows/block, 4 waves (col-split) ====================
__global__ __launch_bounds__(256)
void fused_gemms(const unsigned short* __restrict__ xb,
                 const unsigned short* __restrict__ pw1, const unsigned short* __restrict__ pw2,
                 const unsigned short* __restrict__ pw3,
                 const float* __restrict__ b1, const float* __restrict__ b2,
                 const float* __restrict__ cn2g,
                 float* __restrict__ h_out, unsigned short* __restrict__ hWb,
                 unsigned short* __restrict__ qtb, int N)
{
    __shared__ __align__(16) short Xs[16 * 136];       // x, then h (bf16)
    __shared__ __align__(16) float hf32[16 * 132];     // h f32 bounce
    __shared__ __align__(16) unsigned short hWs[16 * 136];  // hW bf16 bounce
    __shared__ __align__(16) unsigned short qts[16 * 72];   // qt bf16 bounce
    __shared__ float hn2s[4][16];

    const int tid = threadIdx.x, wave = tid >> 6, lane = tid & 63;
    const int l15 = lane & 15, l4 = lane >> 4;
    const int rowBlk = blockIdx.x * 16;

    // ---- Phase 1: x = leaky(x_node @ W1^T + b1), K=256 ----
    f32x4 a0{0.f,0.f,0.f,0.f}, a1{0.f,0.f,0.f,0.f}, a2{0.f,0.f,0.f,0.f};
    {
        const unsigned short* ap = xb + (size_t)(rowBlk + l15) * 256 + l4 * 8;
        const unsigned short* bp = pw1 + (size_t)(wave * 2) * 512 + lane * 8;
#pragma unroll
        for (int k = 0; k < 8; k++) {
            bf16x8 af = *reinterpret_cast<const bf16x8*>(ap + k * 32);
            bf16x8 bf0 = *reinterpret_cast<const bf16x8*>(bp + (size_t)k * 8 * 512);
            bf16x8 bf1 = *reinterpret_cast<const bf16x8*>(bp + (size_t)k * 8 * 512 + 512);
            a0 = __builtin_amdgcn_mfma_f32_16x16x32_bf16(af, bf0, a0, 0, 0, 0);
            a1 = __builtin_amdgcn_mfma_f32_16x16x32_bf16(af, bf1, a1, 0, 0, 0);
        }
        float bia = b1[wave * 32 + l15], bib = b1[wave * 32 + 16 + l15];
#pragma unroll
        for (int j = 0; j < 4; j++) {
            Xs[(l4 * 4 + j) * 136 + wave * 32 + l15]      = (short)f2bf(leaky_f(a0[j] + bia));
            Xs[(l4 * 4 + j) * 136 + wave * 32 + 16 + l15] = (short)f2bf(leaky_f(a1[j] + bib));
        }
    }
    __syncthreads();

    // ---- Phase 2: h = leaky(x @ W2^T + b2), K=128 ----
    a0 = f32x4{0.f,0.f,0.f,0.f}; a1 = f32x4{0.f,0.f,0.f,0.f};
    const short* xp = &Xs[l15 * 136 + l4 * 8];
    {
        const unsigned short* bp = pw2 + (size_t)(wave * 2) * 512 + lane * 8;
#pragma unroll
        for (int k = 0; k < 4; k++) {
            bf16x8 af = *reinterpret_cast<const bf16x8*>(xp + k * 32);
            bf16x8 bf0 = *reinterpret_cast<const bf16x8*>(bp + (size_t)k * 8 * 512);
            bf16x8 bf1 = *reinterpret_cast<const bf16x8*>(bp + (size_t)k * 8 * 512 + 512);
            a0 = __builtin_amdgcn_mfma_f32_16x16x32_bf16(af, bf0, a0, 0, 0, 0);
            a1 = __builtin_amdgcn_mfma_f32_16x16x32_bf16(af, bf1, a1, 0, 0, 0);
        }
    }
    float hv0[4], hv1[4], pn[4];
    {
        float bia = b2[wave * 32 + l15], bib = b2[wave * 32 + 16 + l15];
#pragma unroll
        for (int j = 0; j < 4; j++) {
            hv0[j] = leaky_f(a0[j] + bia);
            hv1[j] = leaky_f(a1[j] + bib);
            float s = hv0[j] * hv0[j] + hv1[j] * hv1[j];
            s += __shfl_xor(s, 1); s += __shfl_xor(s, 2);
            s += __shfl_xor(s, 4); s += __shfl_xor(s, 8);
            pn[j] = s;
        }
    }
    __syncthreads();   // all waves done reading Xs(x); h still in registers

#pragma unroll
    for (int j = 0; j < 4; j++) {
        int r = l4 * 4 + j;
        hf32[r * 132 + wave * 32 + l15]      = hv0[j];
        hf32[r * 132 + wave * 32 + 16 + l15] = hv1[j];
        Xs[r * 136 + wave * 32 + l15]      = (short)f2bf(hv0[j]);
        Xs[r * 136 + wave * 32 + 16 + l15] = (short)f2bf(hv1[j]);
        if (l15 == 0) hn2s[wave][r] = pn[j];
    }
    __syncthreads();   // h ready in LDS

    // ---- coalesced h_out store ----
    {
        int r = tid >> 4, c0 = (tid & 15) * 8;
        f32x4 v0 = *reinterpret_cast<const f32x4*>(&hf32[r * 132 + c0]);
        f32x4 v1 = *reinterpret_cast<const f32x4*>(&hf32[r * 132 + c0 + 4]);
        float* dst = h_out + (size_t)(rowBlk + r) * 128 + c0;
        __builtin_nontemporal_store(v0, reinterpret_cast<f32x4*>(dst));
        __builtin_nontemporal_store(v1, reinterpret_cast<f32x4*>(dst + 4));
    }

    // ---- Phase 3: [hW | q] = h @ [W21;cent]^T, K=128, 192 cols ----
    a0 = f32x4{0.f,0.f,0.f,0.f}; a1 = f32x4{0.f,0.f,0.f,0.f}; a2 = f32x4{0.f,0.f,0.f,0.f};
    {
        const unsigned short* bp = pw3 + (size_t)(wave * 3) * 512 + lane * 8;
#pragma unroll
        for (int k = 0; k < 4; k++) {
            bf16x8 af = *reinterpret_cast<const bf16x8*>(xp + k * 32);
            bf16x8 bf0 = *reinterpret_cast<const bf16x8*>(bp + (size_t)k * 12 * 512);
            bf16x8 bf1 = *reinterpret_cast<const bf16x8*>(bp + (size_t)k * 12 * 512 + 512);
            bf16x8 bf2 = *reinterpret_cast<const bf16x8*>(bp + (size_t)k * 12 * 512 + 1024);
            a0 = __builtin_amdgcn_mfma_f32_16x16x32_bf16(af, bf0, a0, 0, 0, 0);
            a1 = __builtin_amdgcn_mfma_f32_16x16x32_bf16(af, bf1, a1, 0, 0, 0);
            a2 = __builtin_amdgcn_mfma_f32_16x16x32_bf16(af, bf2, a2, 0, 0, 0);
        }
    }
    {
        float hn2r[4];
#pragma unroll
        for (int j = 0; j < 4; j++)
            hn2r[j] = hn2s[0][l4 * 4 + j] + hn2s[1][l4 * 4 + j]
                    + hn2s[2][l4 * 4 + j] + hn2s[3][l4 * 4 + j];
        f32x4 av[3] = {a0, a1, a2};
#pragma unroll
        for (int ff = 0; ff < 3; ff++) {
            int col = wave * 48 + ff * 16 + l15;
            if (col < 128) {
#pragma unroll
                for (int j = 0; j < 4; j++)
                    hWs[(l4 * 4 + j) * 136 + col] = f2bf(av[ff][j]);
            } else {
                int c2 = col - 128;
                float cn2v = cn2g[c2];
#pragma unroll
                for (int j = 0; j < 4; j++) {
                    float q = 1.f / (1.f + cn2v + hn2r[j] - 2.f * av[ff][j]);
                    qts[(l4 * 4 + j) * 72 + c2] = f2bf(q);
                }
            }
        }
    }
    __syncthreads();

    // ---- coalesced hWb + qtb stores ----
    {
        int r = tid >> 4, c0 = (tid & 15) * 8;
        *reinterpret_cast<u16x8*>(hWb + (size_t)(rowBlk + r) * 128 + c0) =
            *reinterpret_cast<const u16x8*>(&hWs[r * 136 + c0]);
        int cq = (tid & 15) * 4;
        *reinterpret_cast<u16x4*>(qtb + (size_t)(rowBlk + r) * 64 + cq) =
            *reinterpret_cast<const u16x4*>(&qts[r * 72 + cq]);
    }
}

// ==================== per-node aggregation: 2 nodes per wave, pipelined, barrier-free ====================
// Both nodes' q-tiles staged at entry (one vmcnt covers all) -> node1's gather latency
// hides under node0's softmax+PV. hW register-direct (R14-validated). All LDS wave-private.
struct PerWave {
    unsigned short qs[2][1024];   // 4 KB: staged q rows for node 0/1
    float wbuf[16][16];           // 1 KB: softmax weights (reused across nodes, same-wave ordered)
};

__global__ __launch_bounds__(256)
void agg_kernel(const int* __restrict__ adj, const unsigned short* __restrict__ qtb,
                const unsigned short* __restrict__ hWb, const float* __restrict__ b21,
                const float* __restrict__ headConv, float* __restrict__ out1)
{
    __shared__ __align__(16) PerWave upw[4];   // 20 KB/block

    const int wv = threadIdx.x >> 6, lane = threadIdx.x & 63;
    const int eg = lane >> 4, l15 = lane & 15;
    const int n0 = (blockIdx.x * 4 + wv) * 2;

    const int adjv0 = adj[(size_t)n0 * 16 + l15];
    const int adjv1 = adj[(size_t)n0 * 16 + 16 + l15];

    // stage q for BOTH nodes upfront (4 independent coalesced 128B-row loads)
#pragma unroll
    for (int i = 0; i < 2; i++) {
        int row = i * 8 + (lane >> 3);
        int nb0 = __shfl(adjv0, row);
        int nb1 = __shfl(adjv1, row);
        *reinterpret_cast<u16x8*>(&upw[wv].qs[0][i * 512 + lane * 8]) =
            *reinterpret_cast<const u16x8*>(qtb + (size_t)nb0 * 64 + (lane & 7) * 8);
        *reinterpret_cast<u16x8*>(&upw[wv].qs[1][i * 512 + lane * 8]) =
            *reinterpret_cast<const u16x8*>(qtb + (size_t)nb1 * 64 + (lane & 7) * 8);
    }

    // neighbor ids for both nodes (readlane, immediate lane -> SALU)
    int nbs0[16], nbs1[16];
#pragma unroll
    for (int e = 0; e < 16; e++) { nbs0[e] = __shfl(adjv0, e); nbs1[e] = __shfl(adjv1, e); }

    const float conv = headConv[eg];
    const int d0 = l15 * 4;
    float bvf[8];
    *reinterpret_cast<float4*>(bvf)     = *reinterpret_cast<const float4*>(b21 + d0);
    *reinterpret_cast<float4*>(bvf + 4) = *reinterpret_cast<const float4*>(b21 + d0 + 64);

#pragma unroll
    for (int node = 0; node < 2; node++) {
        const int* nbs = node ? nbs1 : nbs0;

        // ---- softmax (lane = hc): neighbor-sum + logits via shfl; exp own e-quarter ----
        {
            float qv[16];
            float s = 0.f;
#pragma unroll
            for (int e = 0; e < 16; e++) {
                qv[e] = bf2f(upw[wv].qs[node][e * 64 + lane]);
                s += qv[e];
            }
            float rs = 1.f / s;
            float t[16];
#pragma unroll
            for (int e = 0; e < 16; e++) {
                float v = conv * qv[e] * rs;
                v += __shfl_xor(v, 16);
                v += __shfl_xor(v, 32);       // all lanes hold logit[c=l15][e]
                t[e] = v;
            }
            float m = fmaxf(fmaxf(t[eg * 4], t[eg * 4 + 1]), fmaxf(t[eg * 4 + 2], t[eg * 4 + 3]));
            m = fmaxf(m, __shfl_xor(m, 16));
            m = fmaxf(m, __shfl_xor(m, 32));
            float ex[4];
            float ps = 0.f;
#pragma unroll
            for (int j = 0; j < 4; j++) { ex[j] = __expf(t[eg * 4 + j] - m); ps += ex[j]; }
            ps += __shfl_xor(ps, 16);
            ps += __shfl_xor(ps, 32);
            float inv = 1.f / ps;
#pragma unroll
            for (int j = 0; j < 4; j++) upw[wv].wbuf[eg * 4 + j][l15] = ex[j] * inv;
            // no barrier: wave-private, DS in-order
        }

        // ---- PV: lane (cg=eg, dg=l15) covers c = eg*4+jc, d = l15*4..+3 and +64..+67 ----
        {
            f32x2 acc2[4][4];
#pragma unroll
            for (int jc = 0; jc < 4; jc++) {
                acc2[jc][0] = f32x2{bvf[0], bvf[1]};
                acc2[jc][1] = f32x2{bvf[2], bvf[3]};
                acc2[jc][2] = f32x2{bvf[4], bvf[5]};
                acc2[jc][3] = f32x2{bvf[6], bvf[7]};
            }

#pragma unroll
            for (int e = 0; e < 16; e++) {
                const unsigned short* hrow = hWb + (size_t)nbs[e] * 128;
                uint2 wlo = *reinterpret_cast<const uint2*>(hrow + d0);      // 8B, grp=128B line
                uint2 whi = *reinterpret_cast<const uint2*>(hrow + 64 + d0); // 8B, +128B
                float w4[4];
                *reinterpret_cast<float4*>(w4) =
                    *reinterpret_cast<const float4*>(&upw[wv].wbuf[e][eg * 4]);  // ds_read_b128
                f32x2 hv2[4];
                hv2[0] = f32x2{bflo(wlo.x), bfhi(wlo.x)};
                hv2[1] = f32x2{bflo(wlo.y), bfhi(wlo.y)};
                hv2[2] = f32x2{bflo(whi.x), bfhi(whi.x)};
                hv2[3] = f32x2{bflo(whi.y), bfhi(whi.y)};
#pragma unroll
                for (int jc = 0; jc < 4; jc++) {
                    f32x2 w2 = f32x2{w4[jc], w4[jc]};
#pragma unroll
                    for (int q = 0; q < 4; q++)
                        acc2[jc][q] = fma2(w2, hv2[q], acc2[jc][q]);
                }
            }

#pragma unroll
            for (int jc = 0; jc < 4; jc++) {
                f32x4 lo, hi;
                lo[0] = leaky_f(acc2[jc][0][0]); lo[1] = leaky_f(acc2[jc][0][1]);
                lo[2] = leaky_f(acc2[jc][1][0]); lo[3] = leaky_f(acc2[jc][1][1]);
                hi[0] = leaky_f(acc2[jc][2][0]); hi[1] = leaky_f(acc2[jc][2][1]);
                hi[2] = leaky_f(acc2[jc][3][0]); hi[3] = leaky_f(acc2[jc][3][1]);
                float* dst = out1 + ((size_t)((n0 + node) * 16 + eg * 4 + jc)) * 128;
                __builtin_nontemporal_store(lo, reinterpret_cast<f32x4*>(dst + d0));
                __builtin_nontemporal_store(hi, reinterpret_cast<f32x4*>(dst + d0 + 64));
            }
        }
    }
}

extern "C" void kernel_launch(void* const* d_in, const int* in_sizes, int n_in,
                              void* d_out, int out_size, void* d_ws, size_t ws_size,
                              hipStream_t stream)
{
    const float* x_node   = (const float*)d_in[0];
    const int*   adj      = (const int*)  d_in[1];
    const float* W1       = (const float*)d_in[3];
    const float* b1       = (const float*)d_in[4];
    const float* W2       = (const float*)d_in[5];
    const float* b2       = (const float*)d_in[6];
    const float* W21      = (const float*)d_in[7];
    const float* b21      = (const float*)d_in[8];
    const float* cent     = (const float*)d_in[9];
    const float* headConv = (const float*)d_in[10];

    const int N = in_sizes[0] / 256;     // 20000

    float* h    = (float*)d_out;                 // h_prime [N][128]
    float* out1 = h + (size_t)N * 128;           // new_feat [N][16][128]

    unsigned short* xb  = (unsigned short*)d_ws;       // [N][256] bf16
    unsigned short* hWb = xb  + (size_t)N * 256;       // [N][128] bf16
    unsigned short* qtb = hWb + (size_t)N * 128;       // [N][64]  bf16
    unsigned short* pw1 = qtb + (size_t)N * 64;        // 32768
    unsigned short* pw2 = pw1 + 32768;                 // 16384
    unsigned short* pw3 = pw2 + 16384;                 // 24576
    float*          cn2g = (float*)(pw3 + 24576);      // [64]

    const int xblocks = (N * 256) / 4096;              // 1250

    pack_kernel<<<37 + xblocks, 256, 0, stream>>>(x_node, W1, W2, W21, cent,
                                                  xb, pw1, pw2, pw3, cn2g, N);
    fused_gemms<<<N / 16, 256, 0, stream>>>(xb, pw1, pw2, pw3, b1, b2, cn2g,
                                            h, hWb, qtb, N);
    agg_kernel<<<N / 8, 256, 0, stream>>>(adj, qtb, hWb, b21, headConv, out1);
}

// Round 16
// 68.881 us; speedup vs baseline: 1.3046x; 1.3046x over previous
//
#include <hip/hip_runtime.h>
#include <cstdint>
#include <cstddef>

#define NEG_SLOPE 0.2f

typedef __attribute__((ext_vector_type(8))) short bf16x8;
typedef __attribute__((ext_vector_type(8))) unsigned short u16x8;
typedef __attribute__((ext_vector_type(4))) unsigned short u16x4;
typedef __attribute__((ext_vector_type(4))) float f32x4;
typedef __attribute__((ext_vector_type(2))) float f32x2;

__device__ __forceinline__ float leaky_f(float x) { return x >= 0.f ? x : NEG_SLOPE * x; }

__device__ __forceinline__ unsigned short f2bf(float f) {
    union { float f; uint32_t u; } v; v.f = f;
    return (unsigned short)((v.u + 0x7fffu + ((v.u >> 16) & 1u)) >> 16);
}
__device__ __forceinline__ float bf2f(unsigned short u) {
    union { uint32_t u; float f; } v; v.u = ((uint32_t)u) << 16; return v.f;
}
__device__ __forceinline__ float bfhi(uint32_t w) {
    union { uint32_t u; float f; } v; v.u = w & 0xffff0000u; return v.f;
}
__device__ __forceinline__ float bflo(uint32_t w) {
    union { uint32_t u; float f; } v; v.u = w << 16; return v.f;
}
__device__ __forceinline__ u16x8 cvt8(float4 a, float4 b) {
    u16x8 o;
    o[0] = f2bf(a.x); o[1] = f2bf(a.y); o[2] = f2bf(a.z); o[3] = f2bf(a.w);
    o[4] = f2bf(b.x); o[5] = f2bf(b.y); o[6] = f2bf(b.z); o[7] = f2bf(b.w);
    return o;
}

#if __has_builtin(__builtin_elementwise_fma)
__device__ __forceinline__ f32x2 fma2(f32x2 a, f32x2 b, f32x2 c) {
    return __builtin_elementwise_fma(a, b, c);
}
#else
__device__ __forceinline__ f32x2 fma2(f32x2 a, f32x2 b, f32x2 c) {
    f32x2 r; r[0] = fmaf(a[0], b[0], c[0]); r[1] = fmaf(a[1], b[1], c[1]); return r;
}
#endif

// ==================== pack: weights -> fragment-ready bf16; x_node -> bf16; cn2 ====================
__global__ __launch_bounds__(256)
void pack_kernel(const float* __restrict__ x_node, const float* __restrict__ W1,
                 const float* __restrict__ W2, const float* __restrict__ W21,
                 const float* __restrict__ cent,
                 unsigned short* __restrict__ xb, unsigned short* __restrict__ pw1,
                 unsigned short* __restrict__ pw2, unsigned short* __restrict__ pw3,
                 float* __restrict__ cn2g, int N)
{
    const int bid = blockIdx.x, tid = threadIdx.x;
    if (bid < 36) {                       // 144 weight fragments, 4 per block
        const int sub = tid >> 6, lane = tid & 63, g = bid * 4 + sub;
        const int l15 = lane & 15, l4 = lane >> 4;
        const float* src; unsigned short* dst;
        if (g < 64) {        // W1: 8 steps x 8 frags, K=256
            int step = g >> 3, f = g & 7;
            src = W1 + (size_t)(f * 16 + l15) * 256 + step * 32 + l4 * 8;
            dst = pw1 + ((size_t)(step * 8 + f) * 64 + lane) * 8;
        } else if (g < 96) { // W2: 4 steps x 8 frags, K=128
            int gg = g - 64, step = gg >> 3, f = gg & 7;
            src = W2 + (size_t)(f * 16 + l15) * 128 + step * 32 + l4 * 8;
            dst = pw2 + ((size_t)(step * 8 + f) * 64 + lane) * 8;
        } else {             // [W21;cent]: 4 steps x 12 frags, K=128
            int gg = g - 96, step = gg / 12, f = gg % 12;
            int brow = f * 16 + l15;
            const float* base = (brow < 128) ? (W21 + (size_t)brow * 128)
                                             : (cent + (size_t)(brow - 128) * 128);
            src = base + step * 32 + l4 * 8;
            dst = pw3 + ((size_t)(step * 12 + f) * 64 + lane) * 8;
        }
        float4 a = *reinterpret_cast<const float4*>(src);
        float4 b = *reinterpret_cast<const float4*>(src + 4);
        *reinterpret_cast<u16x8*>(dst) = cvt8(a, b);
    } else if (bid == 36) {               // cn2
        int r = tid >> 2, c0 = (tid & 3) * 32;
        const float* cr = cent + (size_t)r * 128 + c0;
        float s = 0.f;
#pragma unroll
        for (int q = 0; q < 8; q++) {
            float4 v = *reinterpret_cast<const float4*>(cr + q * 4);
            s += v.x * v.x + v.y * v.y + v.z * v.z + v.w * v.w;
        }
        s += __shfl_xor(s, 1); s += __shfl_xor(s, 2);
        if ((tid & 3) == 0) cn2g[r] = s;
    } else {                              // x_node -> bf16, 4096 elems/block
        size_t base = (size_t)(bid - 37) * 4096 + (size_t)tid * 16;
        float4 v0 = *reinterpret_cast<const float4*>(x_node + base);
        float4 v1 = *reinterpret_cast<const float4*>(x_node + base + 4);
        float4 v2 = *reinterpret_cast<const float4*>(x_node + base + 8);
        float4 v3 = *reinterpret_cast<const float4*>(x_node + base + 12);
        *reinterpret_cast<u16x8*>(xb + base)     = cvt8(v0, v1);
        *reinterpret_cast<u16x8*>(xb + base + 8) = cvt8(v2, v3);
    }
}

// ==================== fused GEMM chain: 16 rows/block, 4 waves (col-split) ====================
__global__ __launch_bounds__(256)
void fused_gemms(const unsigned short* __restrict__ xb,
                 const unsigned short* __restrict__ pw1, const unsigned short* __restrict__ pw2,
                 const unsigned short* __restrict__ pw3,
                 const float* __restrict__ b1, const float* __restrict__ b2,
                 const float* __restrict__ cn2g,
                 float* __restrict__ h_out, unsigned short* __restrict__ hWb,
                 unsigned short* __restrict__ qtb, int N)
{
    __shared__ __align__(16) short Xs[16 * 136];       // x, then h (bf16)
    __shared__ __align__(16) float hf32[16 * 132];     // h f32 bounce
    __shared__ __align__(16) unsigned short hWs[16 * 136];  // hW bf16 bounce
    __shared__ __align__(16) unsigned short qts[16 * 72];   // qt bf16 bounce
    __shared__ float hn2s[4][16];

    const int tid = threadIdx.x, wave = tid >> 6, lane = tid & 63;
    const int l15 = lane & 15, l4 = lane >> 4;
    const int rowBlk = blockIdx.x * 16;

    // ---- Phase 1: x = leaky(x_node @ W1^T + b1), K=256 ----
    f32x4 a0{0.f,0.f,0.f,0.f}, a1{0.f,0.f,0.f,0.f}, a2{0.f,0.f,0.f,0.f};
    {
        const unsigned short* ap = xb + (size_t)(rowBlk + l15) * 256 + l4 * 8;
        const unsigned short* bp = pw1 + (size_t)(wave * 2) * 512 + lane * 8;
#pragma unroll
        for (int k = 0; k < 8; k++) {
            bf16x8 af = *reinterpret_cast<const bf16x8*>(ap + k * 32);
            bf16x8 bf0 = *reinterpret_cast<const bf16x8*>(bp + (size_t)k * 8 * 512);
            bf16x8 bf1 = *reinterpret_cast<const bf16x8*>(bp + (size_t)k * 8 * 512 + 512);
            a0 = __builtin_amdgcn_mfma_f32_16x16x32_bf16(af, bf0, a0, 0, 0, 0);
            a1 = __builtin_amdgcn_mfma_f32_16x16x32_bf16(af, bf1, a1, 0, 0, 0);
        }
        float bia = b1[wave * 32 + l15], bib = b1[wave * 32 + 16 + l15];
#pragma unroll
        for (int j = 0; j < 4; j++) {
            Xs[(l4 * 4 + j) * 136 + wave * 32 + l15]      = (short)f2bf(leaky_f(a0[j] + bia));
            Xs[(l4 * 4 + j) * 136 + wave * 32 + 16 + l15] = (short)f2bf(leaky_f(a1[j] + bib));
        }
    }
    __syncthreads();

    // ---- Phase 2: h = leaky(x @ W2^T + b2), K=128 ----
    a0 = f32x4{0.f,0.f,0.f,0.f}; a1 = f32x4{0.f,0.f,0.f,0.f};
    const short* xp = &Xs[l15 * 136 + l4 * 8];
    {
        const unsigned short* bp = pw2 + (size_t)(wave * 2) * 512 + lane * 8;
#pragma unroll
        for (int k = 0; k < 4; k++) {
            bf16x8 af = *reinterpret_cast<const bf16x8*>(xp + k * 32);
            bf16x8 bf0 = *reinterpret_cast<const bf16x8*>(bp + (size_t)k * 8 * 512);
            bf16x8 bf1 = *reinterpret_cast<const bf16x8*>(bp + (size_t)k * 8 * 512 + 512);
            a0 = __builtin_amdgcn_mfma_f32_16x16x32_bf16(af, bf0, a0, 0, 0, 0);
            a1 = __builtin_amdgcn_mfma_f32_16x16x32_bf16(af, bf1, a1, 0, 0, 0);
        }
    }
    float hv0[4], hv1[4], pn[4];
    {
        float bia = b2[wave * 32 + l15], bib = b2[wave * 32 + 16 + l15];
#pragma unroll
        for (int j = 0; j < 4; j++) {
            hv0[j] = leaky_f(a0[j] + bia);
            hv1[j] = leaky_f(a1[j] + bib);
            float s = hv0[j] * hv0[j] + hv1[j] * hv1[j];
            s += __shfl_xor(s, 1); s += __shfl_xor(s, 2);
            s += __shfl_xor(s, 4); s += __shfl_xor(s, 8);
            pn[j] = s;
        }
    }
    __syncthreads();   // all waves done reading Xs(x); h still in registers

#pragma unroll
    for (int j = 0; j < 4; j++) {
        int r = l4 * 4 + j;
        hf32[r * 132 + wave * 32 + l15]      = hv0[j];
        hf32[r * 132 + wave * 32 + 16 + l15] = hv1[j];
        Xs[r * 136 + wave * 32 + l15]      = (short)f2bf(hv0[j]);
        Xs[r * 136 + wave * 32 + 16 + l15] = (short)f2bf(hv1[j]);
        if (l15 == 0) hn2s[wave][r] = pn[j];
    }
    __syncthreads();   // h ready in LDS

    // ---- coalesced h_out store ----
    {
        int r = tid >> 4, c0 = (tid & 15) * 8;
        f32x4 v0 = *reinterpret_cast<const f32x4*>(&hf32[r * 132 + c0]);
        f32x4 v1 = *reinterpret_cast<const f32x4*>(&hf32[r * 132 + c0 + 4]);
        float* dst = h_out + (size_t)(rowBlk + r) * 128 + c0;
        __builtin_nontemporal_store(v0, reinterpret_cast<f32x4*>(dst));
        __builtin_nontemporal_store(v1, reinterpret_cast<f32x4*>(dst + 4));
    }

    // ---- Phase 3: [hW | q] = h @ [W21;cent]^T, K=128, 192 cols ----
    a0 = f32x4{0.f,0.f,0.f,0.f}; a1 = f32x4{0.f,0.f,0.f,0.f}; a2 = f32x4{0.f,0.f,0.f,0.f};
    {
        const unsigned short* bp = pw3 + (size_t)(wave * 3) * 512 + lane * 8;
#pragma unroll
        for (int k = 0; k < 4; k++) {
            bf16x8 af = *reinterpret_cast<const bf16x8*>(xp + k * 32);
            bf16x8 bf0 = *reinterpret_cast<const bf16x8*>(bp + (size_t)k * 12 * 512);
            bf16x8 bf1 = *reinterpret_cast<const bf16x8*>(bp + (size_t)k * 12 * 512 + 512);
            bf16x8 bf2 = *reinterpret_cast<const bf16x8*>(bp + (size_t)k * 12 * 512 + 1024);
            a0 = __builtin_amdgcn_mfma_f32_16x16x32_bf16(af, bf0, a0, 0, 0, 0);
            a1 = __builtin_amdgcn_mfma_f32_16x16x32_bf16(af, bf1, a1, 0, 0, 0);
            a2 = __builtin_amdgcn_mfma_f32_16x16x32_bf16(af, bf2, a2, 0, 0, 0);
        }
    }
    {
        float hn2r[4];
#pragma unroll
        for (int j = 0; j < 4; j++)
            hn2r[j] = hn2s[0][l4 * 4 + j] + hn2s[1][l4 * 4 + j]
                    + hn2s[2][l4 * 4 + j] + hn2s[3][l4 * 4 + j];
        f32x4 av[3] = {a0, a1, a2};
#pragma unroll
        for (int ff = 0; ff < 3; ff++) {
            int col = wave * 48 + ff * 16 + l15;
            if (col < 128) {
#pragma unroll
                for (int j = 0; j < 4; j++)
                    hWs[(l4 * 4 + j) * 136 + col] = f2bf(av[ff][j]);
            } else {
                int c2 = col - 128;
                float cn2v = cn2g[c2];
#pragma unroll
                for (int j = 0; j < 4; j++) {
                    float q = 1.f / (1.f + cn2v + hn2r[j] - 2.f * av[ff][j]);
                    qts[(l4 * 4 + j) * 72 + c2] = f2bf(q);
                }
            }
        }
    }
    __syncthreads();

    // ---- coalesced hWb + qtb stores ----
    {
        int r = tid >> 4, c0 = (tid & 15) * 8;
        *reinterpret_cast<u16x8*>(hWb + (size_t)(rowBlk + r) * 128 + c0) =
            *reinterpret_cast<const u16x8*>(&hWs[r * 136 + c0]);
        int cq = (tid & 15) * 4;
        *reinterpret_cast<u16x4*>(qtb + (size_t)(rowBlk + r) * 64 + cq) =
            *reinterpret_cast<const u16x4*>(&qts[r * 72 + cq]);
    }
}

// ==================== per-node aggregation: one wave per node, barrier-free (R12 base) ====================
// ONLY change vs R12: out1 stores are PLAIN (L2 write-back) instead of nontemporal.
struct PerWaveU {
    union {
        unsigned short qs[1024];   // 2 KB: staged q rows [e*64+hc]
        float wbuf[16][16];        // 1 KB: softmax weights [e][c] (after qs consumed)
    };
};

__global__ __launch_bounds__(256)
void agg_kernel(const int* __restrict__ adj, const unsigned short* __restrict__ qtb,
                const unsigned short* __restrict__ hWb, const float* __restrict__ b21,
                const float* __restrict__ headConv, float* __restrict__ out1)
{
    __shared__ __align__(16) unsigned short hs[4][16 * 128];   // 16 KB
    __shared__ __align__(16) PerWaveU upw[4];                  // 8 KB  (total 24 KB)

    const int wv = threadIdx.x >> 6, lane = threadIdx.x & 63;
    const int eg = lane >> 4, l15 = lane & 15;
    const int n = blockIdx.x * 4 + wv;

    const int myadj = adj[n * 16 + l15];

    // stage q (16 rows x 128B) and hW (16 rows x 256B), linear LDS, conflict-free
#pragma unroll
    for (int i = 0; i < 2; i++) {
        int row = i * 8 + (lane >> 3);
        int nb = __shfl(myadj, row);
        *reinterpret_cast<u16x8*>(&upw[wv].qs[i * 512 + lane * 8]) =
            *reinterpret_cast<const u16x8*>(qtb + (size_t)nb * 64 + (lane & 7) * 8);
    }
#pragma unroll
    for (int i = 0; i < 4; i++) {
        int row = i * 4 + eg;
        int nb = __shfl(myadj, row);
        *reinterpret_cast<u16x8*>(&hs[wv][i * 512 + lane * 8]) =
            *reinterpret_cast<const u16x8*>(hWb + (size_t)nb * 128 + l15 * 8);
    }
    // no barrier: wave-private LDS, DS in-order

    // softmax (lane = hc): neighbor-sum + logits via shfl; exp only for own e-quarter
    {
        float qv[16];
        float s = 0.f;
#pragma unroll
        for (int e = 0; e < 16; e++) { qv[e] = bf2f(upw[wv].qs[e * 64 + lane]); s += qv[e]; }
        float rs = 1.f / s;
        float conv = headConv[eg];
        float t[16];
#pragma unroll
        for (int e = 0; e < 16; e++) {
            float v = conv * qv[e] * rs;
            v += __shfl_xor(v, 16);
            v += __shfl_xor(v, 32);       // all lanes hold logit[c=l15][e]
            t[e] = v;
        }
        float m = fmaxf(fmaxf(t[eg * 4], t[eg * 4 + 1]), fmaxf(t[eg * 4 + 2], t[eg * 4 + 3]));
        m = fmaxf(m, __shfl_xor(m, 16));
        m = fmaxf(m, __shfl_xor(m, 32));
        float ex[4];
        float ps = 0.f;
#pragma unroll
        for (int j = 0; j < 4; j++) { ex[j] = __expf(t[eg * 4 + j] - m); ps += ex[j]; }
        ps += __shfl_xor(ps, 16);
        ps += __shfl_xor(ps, 32);
        float inv = 1.f / ps;
#pragma unroll
        for (int j = 0; j < 4; j++) upw[wv].wbuf[eg * 4 + j][l15] = ex[j] * inv;
        // no barrier: same-wave overlay; all qs reads above precede these writes
    }

    // PV: lane (cg=eg, dg=l15) covers c = eg*4+jc, d = l15*4..+3 and +64..+67
    {
        const int d0 = l15 * 4;
        float bvf[8];
        *reinterpret_cast<float4*>(bvf)     = *reinterpret_cast<const float4*>(b21 + d0);
        *reinterpret_cast<float4*>(bvf + 4) = *reinterpret_cast<const float4*>(b21 + d0 + 64);
        f32x2 acc2[4][4];
#pragma unroll
        for (int jc = 0; jc < 4; jc++) {
            acc2[jc][0] = f32x2{bvf[0], bvf[1]};
            acc2[jc][1] = f32x2{bvf[2], bvf[3]};
            acc2[jc][2] = f32x2{bvf[4], bvf[5]};
            acc2[jc][3] = f32x2{bvf[6], bvf[7]};
        }

#pragma unroll
        for (int e = 0; e < 16; e++) {
            uint2 wlo = *reinterpret_cast<const uint2*>(&hs[wv][e * 128 + d0]);
            uint2 whi = *reinterpret_cast<const uint2*>(&hs[wv][e * 128 + 64 + d0]);
            float w4[4];
            *reinterpret_cast<float4*>(w4) =
                *reinterpret_cast<const float4*>(&upw[wv].wbuf[e][eg * 4]);  // ds_read_b128
            f32x2 hv2[4];
            hv2[0] = f32x2{bflo(wlo.x), bfhi(wlo.x)};
            hv2[1] = f32x2{bflo(wlo.y), bfhi(wlo.y)};
            hv2[2] = f32x2{bflo(whi.x), bfhi(whi.x)};
            hv2[3] = f32x2{bflo(whi.y), bfhi(whi.y)};
#pragma unroll
            for (int jc = 0; jc < 4; jc++) {
                f32x2 w2 = f32x2{w4[jc], w4[jc]};
#pragma unroll
                for (int q = 0; q < 4; q++)
                    acc2[jc][q] = fma2(w2, hv2[q], acc2[jc][q]);
            }
        }

#pragma unroll
        for (int jc = 0; jc < 4; jc++) {
            f32x4 lo, hi;
            lo[0] = leaky_f(acc2[jc][0][0]); lo[1] = leaky_f(acc2[jc][0][1]);
            lo[2] = leaky_f(acc2[jc][1][0]); lo[3] = leaky_f(acc2[jc][1][1]);
            hi[0] = leaky_f(acc2[jc][2][0]); hi[1] = leaky_f(acc2[jc][2][1]);
            hi[2] = leaky_f(acc2[jc][3][0]); hi[3] = leaky_f(acc2[jc][3][1]);
            float* dst = out1 + ((size_t)(n * 16 + eg * 4 + jc)) * 128;
            *reinterpret_cast<f32x4*>(dst + d0)      = lo;   // PLAIN store (was nt)
            *reinterpret_cast<f32x4*>(dst + d0 + 64) = hi;   // PLAIN store (was nt)
        }
    }
}

extern "C" void kernel_launch(void* const* d_in, const int* in_sizes, int n_in,
                              void* d_out, int out_size, void* d_ws, size_t ws_size,
                              hipStream_t stream)
{
    const float* x_node   = (const float*)d_in[0];
    const int*   adj      = (const int*)  d_in[1];
    const float* W1       = (const float*)d_in[3];
    const float* b1       = (const float*)d_in[4];
    const float* W2       = (const float*)d_in[5];
    const float* b2       = (const float*)d_in[6];
    const float* W21      = (const float*)d_in[7];
    const float* b21      = (const float*)d_in[8];
    const float* cent     = (const float*)d_in[9];
    const float* headConv = (const float*)d_in[10];

    const int N = in_sizes[0] / 256;     // 20000

    float* h    = (float*)d_out;                 // h_prime [N][128]
    float* out1 = h + (size_t)N * 128;           // new_feat [N][16][128]

    unsigned short* xb  = (unsigned short*)d_ws;       // [N][256] bf16
    unsigned short* hWb = xb  + (size_t)N * 256;       // [N][128] bf16
    unsigned short* qtb = hWb + (size_t)N * 128;       // [N][64]  bf16
    unsigned short* pw1 = qtb + (size_t)N * 64;        // 32768
    unsigned short* pw2 = pw1 + 32768;                 // 16384
    unsigned short* pw3 = pw2 + 16384;                 // 24576
    float*          cn2g = (float*)(pw3 + 24576);      // [64]

    const int xblocks = (N * 256) / 4096;              // 1250

    pack_kernel<<<37 + xblocks, 256, 0, stream>>>(x_node, W1, W2, W21, cent,
                                                  xb, pw1, pw2, pw3, cn2g, N);
    fused_gemms<<<N / 16, 256, 0, stream>>>(xb, pw1, pw2, pw3, b1, b2, cn2g,
                                            h, hWb, qtb, N);
    agg_kernel<<<N / 4, 256, 0, stream>>>(adj, qtb, hWb, b21, headConv, out1);
}

// Round 17
// 64.709 us; speedup vs baseline: 1.3888x; 1.0645x over previous
//
#include <hip/hip_runtime.h>
#include <cstdint>
#include <cstddef>

#define NEG_SLOPE 0.2f

typedef __attribute__((ext_vector_type(8))) short bf16x8;
typedef __attribute__((ext_vector_type(8))) unsigned short u16x8;
typedef __attribute__((ext_vector_type(4))) unsigned short u16x4;
typedef __attribute__((ext_vector_type(4))) float f32x4;
typedef __attribute__((ext_vector_type(2))) float f32x2;

__device__ __forceinline__ float leaky_f(float x) { return x >= 0.f ? x : NEG_SLOPE * x; }

__device__ __forceinline__ unsigned short f2bf(float f) {
    union { float f; uint32_t u; } v; v.f = f;
    return (unsigned short)((v.u + 0x7fffu + ((v.u >> 16) & 1u)) >> 16);
}
__device__ __forceinline__ float bf2f(unsigned short u) {
    union { uint32_t u; float f; } v; v.u = ((uint32_t)u) << 16; return v.f;
}
__device__ __forceinline__ float bfhi(uint32_t w) {
    union { uint32_t u; float f; } v; v.u = w & 0xffff0000u; return v.f;
}
__device__ __forceinline__ float bflo(uint32_t w) {
    union { uint32_t u; float f; } v; v.u = w << 16; return v.f;
}
__device__ __forceinline__ u16x8 cvt8(float4 a, float4 b) {
    u16x8 o;
    o[0] = f2bf(a.x); o[1] = f2bf(a.y); o[2] = f2bf(a.z); o[3] = f2bf(a.w);
    o[4] = f2bf(b.x); o[5] = f2bf(b.y); o[6] = f2bf(b.z); o[7] = f2bf(b.w);
    return o;
}

#if __has_builtin(__builtin_elementwise_fma)
__device__ __forceinline__ f32x2 fma2(f32x2 a, f32x2 b, f32x2 c) {
    return __builtin_elementwise_fma(a, b, c);
}
#else
__device__ __forceinline__ f32x2 fma2(f32x2 a, f32x2 b, f32x2 c) {
    f32x2 r; r[0] = fmaf(a[0], b[0], c[0]); r[1] = fmaf(a[1], b[1], c[1]); return r;
}
#endif

// lanes l and l^32 exchange+add via v_permlane32_swap (VALU pipe, not DS)
__device__ __forceinline__ float xor32_add(float v) {
    float y = v;
    asm volatile("v_permlane32_swap_b32 %0, %1" : "+v"(y), "+v"(v));
    return v + y;
}

// ==================== pack: weights -> fragment-ready bf16; x_node -> bf16; cn2 ====================
__global__ __launch_bounds__(256)
void pack_kernel(const float* __restrict__ x_node, const float* __restrict__ W1,
                 const float* __restrict__ W2, const float* __restrict__ W21,
                 const float* __restrict__ cent,
                 unsigned short* __restrict__ xb, unsigned short* __restrict__ pw1,
                 unsigned short* __restrict__ pw2, unsigned short* __restrict__ pw3,
                 float* __restrict__ cn2g, int N)
{
    const int bid = blockIdx.x, tid = threadIdx.x;
    if (bid < 36) {                       // 144 weight fragments, 4 per block
        const int sub = tid >> 6, lane = tid & 63, g = bid * 4 + sub;
        const int l15 = lane & 15, l4 = lane >> 4;
        const float* src; unsigned short* dst;
        if (g < 64) {        // W1: 8 steps x 8 frags, K=256
            int step = g >> 3, f = g & 7;
            src = W1 + (size_t)(f * 16 + l15) * 256 + step * 32 + l4 * 8;
            dst = pw1 + ((size_t)(step * 8 + f) * 64 + lane) * 8;
        } else if (g < 96) { // W2: 4 steps x 8 frags, K=128
            int gg = g - 64, step = gg >> 3, f = gg & 7;
            src = W2 + (size_t)(f * 16 + l15) * 128 + step * 32 + l4 * 8;
            dst = pw2 + ((size_t)(step * 8 + f) * 64 + lane) * 8;
        } else {             // [W21;cent]: 4 steps x 12 frags, K=128
            int gg = g - 96, step = gg / 12, f = gg % 12;
            int brow = f * 16 + l15;
            const float* base = (brow < 128) ? (W21 + (size_t)brow * 128)
                                             : (cent + (size_t)(brow - 128) * 128);
            src = base + step * 32 + l4 * 8;
            dst = pw3 + ((size_t)(step * 12 + f) * 64 + lane) * 8;
        }
        float4 a = *reinterpret_cast<const float4*>(src);
        float4 b = *reinterpret_cast<const float4*>(src + 4);
        *reinterpret_cast<u16x8*>(dst) = cvt8(a, b);
    } else if (bid == 36) {               // cn2
        int r = tid >> 2, c0 = (tid & 3) * 32;
        const float* cr = cent + (size_t)r * 128 + c0;
        float s = 0.f;
#pragma unroll
        for (int q = 0; q < 8; q++) {
            float4 v = *reinterpret_cast<const float4*>(cr + q * 4);
            s += v.x * v.x + v.y * v.y + v.z * v.z + v.w * v.w;
        }
        s += __shfl_xor(s, 1); s += __shfl_xor(s, 2);
        if ((tid & 3) == 0) cn2g[r] = s;
    } else {                              // x_node -> bf16, 4096 elems/block
        size_t base = (size_t)(bid - 37) * 4096 + (size_t)tid * 16;
        float4 v0 = *reinterpret_cast<const float4*>(x_node + base);
        float4 v1 = *reinterpret_cast<const float4*>(x_node + base + 4);
        float4 v2 = *reinterpret_cast<const float4*>(x_node + base + 8);
        float4 v3 = *reinterpret_cast<const float4*>(x_node + base + 12);
        *reinterpret_cast<u16x8*>(xb + base)     = cvt8(v0, v1);
        *reinterpret_cast<u16x8*>(xb + base + 8) = cvt8(v2, v3);
    }
}

// ==================== fused GEMM chain: 16 rows/block, 4 waves (col-split) ====================
__global__ __launch_bounds__(256)
void fused_gemms(const unsigned short* __restrict__ xb,
                 const unsigned short* __restrict__ pw1, const unsigned short* __restrict__ pw2,
                 const unsigned short* __restrict__ pw3,
                 const float* __restrict__ b1, const float* __restrict__ b2,
                 const float* __restrict__ cn2g,
                 float* __restrict__ h_out, unsigned short* __restrict__ hWb,
                 unsigned short* __restrict__ qtb, int N)
{
    __shared__ __align__(16) short Xs[16 * 136];       // x, then h (bf16)
    __shared__ __align__(16) float hf32[16 * 132];     // h f32 bounce
    __shared__ __align__(16) unsigned short hWs[16 * 136];  // hW bf16 bounce
    __shared__ __align__(16) unsigned short qts[16 * 72];   // qt bf16 bounce
    __shared__ float hn2s[4][16];

    const int tid = threadIdx.x, wave = tid >> 6, lane = tid & 63;
    const int l15 = lane & 15, l4 = lane >> 4;
    const int rowBlk = blockIdx.x * 16;

    // ---- Phase 1: x = leaky(x_node @ W1^T + b1), K=256 ----
    f32x4 a0{0.f,0.f,0.f,0.f}, a1{0.f,0.f,0.f,0.f}, a2{0.f,0.f,0.f,0.f};
    {
        const unsigned short* ap = xb + (size_t)(rowBlk + l15) * 256 + l4 * 8;
        const unsigned short* bp = pw1 + (size_t)(wave * 2) * 512 + lane * 8;
#pragma unroll
        for (int k = 0; k < 8; k++) {
            bf16x8 af = *reinterpret_cast<const bf16x8*>(ap + k * 32);
            bf16x8 bf0 = *reinterpret_cast<const bf16x8*>(bp + (size_t)k * 8 * 512);
            bf16x8 bf1 = *reinterpret_cast<const bf16x8*>(bp + (size_t)k * 8 * 512 + 512);
            a0 = __builtin_amdgcn_mfma_f32_16x16x32_bf16(af, bf0, a0, 0, 0, 0);
            a1 = __builtin_amdgcn_mfma_f32_16x16x32_bf16(af, bf1, a1, 0, 0, 0);
        }
        float bia = b1[wave * 32 + l15], bib = b1[wave * 32 + 16 + l15];
#pragma unroll
        for (int j = 0; j < 4; j++) {
            Xs[(l4 * 4 + j) * 136 + wave * 32 + l15]      = (short)f2bf(leaky_f(a0[j] + bia));
            Xs[(l4 * 4 + j) * 136 + wave * 32 + 16 + l15] = (short)f2bf(leaky_f(a1[j] + bib));
        }
    }
    __syncthreads();

    // ---- Phase 2: h = leaky(x @ W2^T + b2), K=128 ----
    a0 = f32x4{0.f,0.f,0.f,0.f}; a1 = f32x4{0.f,0.f,0.f,0.f};
    const short* xp = &Xs[l15 * 136 + l4 * 8];
    {
        const unsigned short* bp = pw2 + (size_t)(wave * 2) * 512 + lane * 8;
#pragma unroll
        for (int k = 0; k < 4; k++) {
            bf16x8 af = *reinterpret_cast<const bf16x8*>(xp + k * 32);
            bf16x8 bf0 = *reinterpret_cast<const bf16x8*>(bp + (size_t)k * 8 * 512);
            bf16x8 bf1 = *reinterpret_cast<const bf16x8*>(bp + (size_t)k * 8 * 512 + 512);
            a0 = __builtin_amdgcn_mfma_f32_16x16x32_bf16(af, bf0, a0, 0, 0, 0);
            a1 = __builtin_amdgcn_mfma_f32_16x16x32_bf16(af, bf1, a1, 0, 0, 0);
        }
    }
    float hv0[4], hv1[4], pn[4];
    {
        float bia = b2[wave * 32 + l15], bib = b2[wave * 32 + 16 + l15];
#pragma unroll
        for (int j = 0; j < 4; j++) {
            hv0[j] = leaky_f(a0[j] + bia);
            hv1[j] = leaky_f(a1[j] + bib);
            float s = hv0[j] * hv0[j] + hv1[j] * hv1[j];
            s += __shfl_xor(s, 1); s += __shfl_xor(s, 2);
            s += __shfl_xor(s, 4); s += __shfl_xor(s, 8);
            pn[j] = s;
        }
    }
    __syncthreads();   // all waves done reading Xs(x); h still in registers

#pragma unroll
    for (int j = 0; j < 4; j++) {
        int r = l4 * 4 + j;
        hf32[r * 132 + wave * 32 + l15]      = hv0[j];
        hf32[r * 132 + wave * 32 + 16 + l15] = hv1[j];
        Xs[r * 136 + wave * 32 + l15]      = (short)f2bf(hv0[j]);
        Xs[r * 136 + wave * 32 + 16 + l15] = (short)f2bf(hv1[j]);
        if (l15 == 0) hn2s[wave][r] = pn[j];
    }
    __syncthreads();   // h ready in LDS

    // ---- coalesced h_out store ----
    {
        int r = tid >> 4, c0 = (tid & 15) * 8;
        f32x4 v0 = *reinterpret_cast<const f32x4*>(&hf32[r * 132 + c0]);
        f32x4 v1 = *reinterpret_cast<const f32x4*>(&hf32[r * 132 + c0 + 4]);
        float* dst = h_out + (size_t)(rowBlk + r) * 128 + c0;
        __builtin_nontemporal_store(v0, reinterpret_cast<f32x4*>(dst));
        __builtin_nontemporal_store(v1, reinterpret_cast<f32x4*>(dst + 4));
    }

    // ---- Phase 3: [hW | q] = h @ [W21;cent]^T, K=128, 192 cols ----
    a0 = f32x4{0.f,0.f,0.f,0.f}; a1 = f32x4{0.f,0.f,0.f,0.f}; a2 = f32x4{0.f,0.f,0.f,0.f};
    {
        const unsigned short* bp = pw3 + (size_t)(wave * 3) * 512 + lane * 8;
#pragma unroll
        for (int k = 0; k < 4; k++) {
            bf16x8 af = *reinterpret_cast<const bf16x8*>(xp + k * 32);
            bf16x8 bf0 = *reinterpret_cast<const bf16x8*>(bp + (size_t)k * 12 * 512);
            bf16x8 bf1 = *reinterpret_cast<const bf16x8*>(bp + (size_t)k * 12 * 512 + 512);
            bf16x8 bf2 = *reinterpret_cast<const bf16x8*>(bp + (size_t)k * 12 * 512 + 1024);
            a0 = __builtin_amdgcn_mfma_f32_16x16x32_bf16(af, bf0, a0, 0, 0, 0);
            a1 = __builtin_amdgcn_mfma_f32_16x16x32_bf16(af, bf1, a1, 0, 0, 0);
            a2 = __builtin_amdgcn_mfma_f32_16x16x32_bf16(af, bf2, a2, 0, 0, 0);
        }
    }
    {
        float hn2r[4];
#pragma unroll
        for (int j = 0; j < 4; j++)
            hn2r[j] = hn2s[0][l4 * 4 + j] + hn2s[1][l4 * 4 + j]
                    + hn2s[2][l4 * 4 + j] + hn2s[3][l4 * 4 + j];
        f32x4 av[3] = {a0, a1, a2};
#pragma unroll
        for (int ff = 0; ff < 3; ff++) {
            int col = wave * 48 + ff * 16 + l15;
            if (col < 128) {
#pragma unroll
                for (int j = 0; j < 4; j++)
                    hWs[(l4 * 4 + j) * 136 + col] = f2bf(av[ff][j]);
            } else {
                int c2 = col - 128;
                float cn2v = cn2g[c2];
#pragma unroll
                for (int j = 0; j < 4; j++) {
                    float q = 1.f / (1.f + cn2v + hn2r[j] - 2.f * av[ff][j]);
                    qts[(l4 * 4 + j) * 72 + c2] = f2bf(q);
                }
            }
        }
    }
    __syncthreads();

    // ---- coalesced hWb + qtb stores ----
    {
        int r = tid >> 4, c0 = (tid & 15) * 8;
        *reinterpret_cast<u16x8*>(hWb + (size_t)(rowBlk + r) * 128 + c0) =
            *reinterpret_cast<const u16x8*>(&hWs[r * 136 + c0]);
        int cq = (tid & 15) * 4;
        *reinterpret_cast<u16x4*>(qtb + (size_t)(rowBlk + r) * 64 + cq) =
            *reinterpret_cast<const u16x4*>(&qts[r * 72 + cq]);
    }
}

// ==================== per-node aggregation: one wave per node, barrier-free (R12 base) ====================
// vs R12: xor-32 reduces moved DS->VALU via v_permlane32_swap; max-subtract dropped
// (logits bounded: |t| <= sum_h |conv_h| <= 6.2, exp <= 500, f32-safe; softmax shift-invariant);
// no runtime-indexed t[16] array (compile-time ex[e&3] + select). Stores = nt (R12-proven).
struct PerWaveU {
    union {
        unsigned short qs[1024];   // 2 KB: staged q rows [e*64+hc]
        float wbuf[16][16];        // 1 KB: softmax weights [e][c] (after qs consumed)
    };
};

__global__ __launch_bounds__(256)
void agg_kernel(const int* __restrict__ adj, const unsigned short* __restrict__ qtb,
                const unsigned short* __restrict__ hWb, const float* __restrict__ b21,
                const float* __restrict__ headConv, float* __restrict__ out1)
{
    __shared__ __align__(16) unsigned short hs[4][16 * 128];   // 16 KB
    __shared__ __align__(16) PerWaveU upw[4];                  // 8 KB  (total 24 KB)

    const int wv = threadIdx.x >> 6, lane = threadIdx.x & 63;
    const int eg = lane >> 4, l15 = lane & 15;
    const int n = blockIdx.x * 4 + wv;

    const int myadj = adj[n * 16 + l15];

    // stage q (16 rows x 128B) and hW (16 rows x 256B), linear LDS, conflict-free
#pragma unroll
    for (int i = 0; i < 2; i++) {
        int row = i * 8 + (lane >> 3);
        int nb = __shfl(myadj, row);
        *reinterpret_cast<u16x8*>(&upw[wv].qs[i * 512 + lane * 8]) =
            *reinterpret_cast<const u16x8*>(qtb + (size_t)nb * 64 + (lane & 7) * 8);
    }
#pragma unroll
    for (int i = 0; i < 4; i++) {
        int row = i * 4 + eg;
        int nb = __shfl(myadj, row);
        *reinterpret_cast<u16x8*>(&hs[wv][i * 512 + lane * 8]) =
            *reinterpret_cast<const u16x8*>(hWb + (size_t)nb * 128 + l15 * 8);
    }
    // no barrier: wave-private LDS, DS in-order

    // softmax (lane = hc): neighbor-sum + logits; xor16 via shfl (DS), xor32 via permlane (VALU)
    {
        float qv[16];
        float s = 0.f;
#pragma unroll
        for (int e = 0; e < 16; e++) { qv[e] = bf2f(upw[wv].qs[e * 64 + lane]); s += qv[e]; }
        float rs = 1.f / s;
        float conv = headConv[eg];
        float ex[4] = {0.f, 0.f, 0.f, 0.f};
#pragma unroll
        for (int e = 0; e < 16; e++) {
            float v = conv * qv[e] * rs;
            v += __shfl_xor(v, 16);
            v = xor32_add(v);             // all lanes hold logit[c=l15][e]
            float evv = __expf(v);        // no max-subtract: |v| <= 6.2
            bool mine = (eg == (e >> 2));
            ex[e & 3] = mine ? evv : ex[e & 3];   // compile-time index, cndmask select
        }
        float ps = ex[0] + ex[1] + ex[2] + ex[3];
        ps += __shfl_xor(ps, 16);
        ps = xor32_add(ps);
        float inv = 1.f / ps;
#pragma unroll
        for (int j = 0; j < 4; j++) upw[wv].wbuf[eg * 4 + j][l15] = ex[j] * inv;
        // no barrier: same-wave overlay; all qs reads above precede these writes
    }

    // PV: lane (cg=eg, dg=l15) covers c = eg*4+jc, d = l15*4..+3 and +64..+67
    {
        const int d0 = l15 * 4;
        float bvf[8];
        *reinterpret_cast<float4*>(bvf)     = *reinterpret_cast<const float4*>(b21 + d0);
        *reinterpret_cast<float4*>(bvf + 4) = *reinterpret_cast<const float4*>(b21 + d0 + 64);
        f32x2 acc2[4][4];
#pragma unroll
        for (int jc = 0; jc < 4; jc++) {
            acc2[jc][0] = f32x2{bvf[0], bvf[1]};
            acc2[jc][1] = f32x2{bvf[2], bvf[3]};
            acc2[jc][2] = f32x2{bvf[4], bvf[5]};
            acc2[jc][3] = f32x2{bvf[6], bvf[7]};
        }

#pragma unroll
        for (int e = 0; e < 16; e++) {
            uint2 wlo = *reinterpret_cast<const uint2*>(&hs[wv][e * 128 + d0]);
            uint2 whi = *reinterpret_cast<const uint2*>(&hs[wv][e * 128 + 64 + d0]);
            float w4[4];
            *reinterpret_cast<float4*>(w4) =
                *reinterpret_cast<const float4*>(&upw[wv].wbuf[e][eg * 4]);  // ds_read_b128
            f32x2 hv2[4];
            hv2[0] = f32x2{bflo(wlo.x), bfhi(wlo.x)};
            hv2[1] = f32x2{bflo(wlo.y), bfhi(wlo.y)};
            hv2[2] = f32x2{bflo(whi.x), bfhi(whi.x)};
            hv2[3] = f32x2{bflo(whi.y), bfhi(whi.y)};
#pragma unroll
            for (int jc = 0; jc < 4; jc++) {
                f32x2 w2 = f32x2{w4[jc], w4[jc]};
#pragma unroll
                for (int q = 0; q < 4; q++)
                    acc2[jc][q] = fma2(w2, hv2[q], acc2[jc][q]);
            }
        }

#pragma unroll
        for (int jc = 0; jc < 4; jc++) {
            f32x4 lo, hi;
            lo[0] = leaky_f(acc2[jc][0][0]); lo[1] = leaky_f(acc2[jc][0][1]);
            lo[2] = leaky_f(acc2[jc][1][0]); lo[3] = leaky_f(acc2[jc][1][1]);
            hi[0] = leaky_f(acc2[jc][2][0]); hi[1] = leaky_f(acc2[jc][2][1]);
            hi[2] = leaky_f(acc2[jc][3][0]); hi[3] = leaky_f(acc2[jc][3][1]);
            float* dst = out1 + ((size_t)(n * 16 + eg * 4 + jc)) * 128;
            __builtin_nontemporal_store(lo, reinterpret_cast<f32x4*>(dst + d0));
            __builtin_nontemporal_store(hi, reinterpret_cast<f32x4*>(dst + d0 + 64));
        }
    }
}

extern "C" void kernel_launch(void* const* d_in, const int* in_sizes, int n_in,
                              void* d_out, int out_size, void* d_ws, size_t ws_size,
                              hipStream_t stream)
{
    const float* x_node   = (const float*)d_in[0];
    const int*   adj      = (const int*)  d_in[1];
    const float* W1       = (const float*)d_in[3];
    const float* b1       = (const float*)d_in[4];
    const float* W2       = (const float*)d_in[5];
    const float* b2       = (const float*)d_in[6];
    const float* W21      = (const float*)d_in[7];
    const float* b21      = (const float*)d_in[8];
    const float* cent     = (const float*)d_in[9];
    const float* headConv = (const float*)d_in[10];

    const int N = in_sizes[0] / 256;     // 20000

    float* h    = (float*)d_out;                 // h_prime [N][128]
    float* out1 = h + (size_t)N * 128;           // new_feat [N][16][128]

    unsigned short* xb  = (unsigned short*)d_ws;       // [N][256] bf16
    unsigned short* hWb = xb  + (size_t)N * 256;       // [N][128] bf16
    unsigned short* qtb = hWb + (size_t)N * 128;       // [N][64]  bf16
    unsigned short* pw1 = qtb + (size_t)N * 64;        // 32768
    unsigned short* pw2 = pw1 + 32768;                 // 16384
    unsigned short* pw3 = pw2 + 16384;                 // 24576
    float*          cn2g = (float*)(pw3 + 24576);      // [64]

    const int xblocks = (N * 256) / 4096;              // 1250

    pack_kernel<<<37 + xblocks, 256, 0, stream>>>(x_node, W1, W2, W21, cent,
                                                  xb, pw1, pw2, pw3, cn2g, N);
    fused_gemms<<<N / 16, 256, 0, stream>>>(xb, pw1, pw2, pw3, b1, b2, cn2g,
                                            h, hWb, qtb, N);
    agg_kernel<<<N / 4, 256, 0, stream>>>(adj, qtb, hWb, b21, headConv, out1);
}

// Round 18
// 64.018 us; speedup vs baseline: 1.4038x; 1.0108x over previous
//
#include <hip/hip_runtime.h>
#include <cstdint>
#include <cstddef>

#define NEG_SLOPE 0.2f

typedef __attribute__((ext_vector_type(8))) short bf16x8;
typedef __attribute__((ext_vector_type(8))) unsigned short u16x8;
typedef __attribute__((ext_vector_type(4))) float f32x4;
typedef __attribute__((ext_vector_type(2))) float f32x2;

__device__ __forceinline__ float leaky_f(float x) { return x >= 0.f ? x : NEG_SLOPE * x; }

__device__ __forceinline__ unsigned short f2bf(float f) {
    union { float f; uint32_t u; } v; v.f = f;
    return (unsigned short)((v.u + 0x7fffu + ((v.u >> 16) & 1u)) >> 16);
}
__device__ __forceinline__ float bf2f(unsigned short u) {
    union { uint32_t u; float f; } v; v.u = ((uint32_t)u) << 16; return v.f;
}
__device__ __forceinline__ float bfhi(uint32_t w) {
    union { uint32_t u; float f; } v; v.u = w & 0xffff0000u; return v.f;
}
__device__ __forceinline__ float bflo(uint32_t w) {
    union { uint32_t u; float f; } v; v.u = w << 16; return v.f;
}
__device__ __forceinline__ u16x8 cvt8(float4 a, float4 b) {
    u16x8 o;
    o[0] = f2bf(a.x); o[1] = f2bf(a.y); o[2] = f2bf(a.z); o[3] = f2bf(a.w);
    o[4] = f2bf(b.x); o[5] = f2bf(b.y); o[6] = f2bf(b.z); o[7] = f2bf(b.w);
    return o;
}

#if __has_builtin(__builtin_elementwise_fma)
__device__ __forceinline__ f32x2 fma2(f32x2 a, f32x2 b, f32x2 c) {
    return __builtin_elementwise_fma(a, b, c);
}
#else
__device__ __forceinline__ f32x2 fma2(f32x2 a, f32x2 b, f32x2 c) {
    f32x2 r; r[0] = fmaf(a[0], b[0], c[0]); r[1] = fmaf(a[1], b[1], c[1]); return r;
}
#endif

// lanes l and l^32 exchange+add via v_permlane32_swap (VALU pipe, not DS)
__device__ __forceinline__ float xor32_add(float v) {
    float y = v;
    asm volatile("v_permlane32_swap_b32 %0, %1" : "+v"(y), "+v"(v));
    return v + y;
}

// ==================== pack: weights -> fragment-ready bf16; x_node -> bf16; cn2 ====================
__global__ __launch_bounds__(256)
void pack_kernel(const float* __restrict__ x_node, const float* __restrict__ W1,
                 const float* __restrict__ W2, const float* __restrict__ W21,
                 const float* __restrict__ cent,
                 unsigned short* __restrict__ xb, unsigned short* __restrict__ pw1,
                 unsigned short* __restrict__ pw2, unsigned short* __restrict__ pw3,
                 float* __restrict__ cn2g, int N)
{
    const int bid = blockIdx.x, tid = threadIdx.x;
    if (bid < 36) {                       // 144 weight fragments, 4 per block
        const int sub = tid >> 6, lane = tid & 63, g = bid * 4 + sub;
        const int l15 = lane & 15, l4 = lane >> 4;
        const float* src; unsigned short* dst;
        if (g < 64) {        // W1: 8 steps x 8 frags, K=256
            int step = g >> 3, f = g & 7;
            src = W1 + (size_t)(f * 16 + l15) * 256 + step * 32 + l4 * 8;
            dst = pw1 + ((size_t)(step * 8 + f) * 64 + lane) * 8;
        } else if (g < 96) { // W2: 4 steps x 8 frags, K=128
            int gg = g - 64, step = gg >> 3, f = gg & 7;
            src = W2 + (size_t)(f * 16 + l15) * 128 + step * 32 + l4 * 8;
            dst = pw2 + ((size_t)(step * 8 + f) * 64 + lane) * 8;
        } else {             // [W21;cent]: 4 steps x 12 frags, K=128
            int gg = g - 96, step = gg / 12, f = gg % 12;
            int brow = f * 16 + l15;
            const float* base = (brow < 128) ? (W21 + (size_t)brow * 128)
                                             : (cent + (size_t)(brow - 128) * 128);
            src = base + step * 32 + l4 * 8;
            dst = pw3 + ((size_t)(step * 12 + f) * 64 + lane) * 8;
        }
        float4 a = *reinterpret_cast<const float4*>(src);
        float4 b = *reinterpret_cast<const float4*>(src + 4);
        *reinterpret_cast<u16x8*>(dst) = cvt8(a, b);
    } else if (bid == 36) {               // cn2
        int r = tid >> 2, c0 = (tid & 3) * 32;
        const float* cr = cent + (size_t)r * 128 + c0;
        float s = 0.f;
#pragma unroll
        for (int q = 0; q < 8; q++) {
            float4 v = *reinterpret_cast<const float4*>(cr + q * 4);
            s += v.x * v.x + v.y * v.y + v.z * v.z + v.w * v.w;
        }
        s += __shfl_xor(s, 1); s += __shfl_xor(s, 2);
        if ((tid & 3) == 0) cn2g[r] = s;
    } else {                              // x_node -> bf16, 4096 elems/block
        size_t base = (size_t)(bid - 37) * 4096 + (size_t)tid * 16;
        float4 v0 = *reinterpret_cast<const float4*>(x_node + base);
        float4 v1 = *reinterpret_cast<const float4*>(x_node + base + 4);
        float4 v2 = *reinterpret_cast<const float4*>(x_node + base + 8);
        float4 v3 = *reinterpret_cast<const float4*>(x_node + base + 12);
        *reinterpret_cast<u16x8*>(xb + base)     = cvt8(v0, v1);
        *reinterpret_cast<u16x8*>(xb + base + 8) = cvt8(v2, v3);
    }
}

// ==================== fused GEMM chain: 32 rows/block, 4 waves, 2 row-frags/wave ====================
// Each B-fragment load feeds TWO MFMAs (rows 0-15 and 16-31) -> per-row B traffic halves,
// block count halves (625). Epilogues: direct stores (R4-proven), LDS = Xs only.
__global__ __launch_bounds__(256)
void fused_gemms(const unsigned short* __restrict__ xb,
                 const unsigned short* __restrict__ pw1, const unsigned short* __restrict__ pw2,
                 const unsigned short* __restrict__ pw3,
                 const float* __restrict__ b1, const float* __restrict__ b2,
                 const float* __restrict__ cn2g,
                 float* __restrict__ h_out, unsigned short* __restrict__ hWb,
                 unsigned short* __restrict__ qtb, int N)
{
    __shared__ __align__(16) short Xs[32 * 136];   // x, then h (bf16)
    __shared__ float hn2s[4][32];

    const int tid = threadIdx.x, wave = tid >> 6, lane = tid & 63;
    const int l15 = lane & 15, l4 = lane >> 4;
    const int rowBlk = blockIdx.x * 32;

    // ---- Phase 1: x = leaky(x_node @ W1^T + b1), K=256 ----
    f32x4 a00{0.f,0.f,0.f,0.f}, a01{0.f,0.f,0.f,0.f}, a10{0.f,0.f,0.f,0.f}, a11{0.f,0.f,0.f,0.f};
    {
        const unsigned short* ap0 = xb + (size_t)(rowBlk + l15) * 256 + l4 * 8;
        const unsigned short* ap1 = ap0 + 16 * 256;
        const unsigned short* bp = pw1 + (size_t)(wave * 2) * 512 + lane * 8;
#pragma unroll
        for (int k = 0; k < 8; k++) {
            bf16x8 af0 = *reinterpret_cast<const bf16x8*>(ap0 + k * 32);
            bf16x8 af1 = *reinterpret_cast<const bf16x8*>(ap1 + k * 32);
            bf16x8 bf0 = *reinterpret_cast<const bf16x8*>(bp + (size_t)k * 8 * 512);
            bf16x8 bf1 = *reinterpret_cast<const bf16x8*>(bp + (size_t)k * 8 * 512 + 512);
            a00 = __builtin_amdgcn_mfma_f32_16x16x32_bf16(af0, bf0, a00, 0, 0, 0);
            a01 = __builtin_amdgcn_mfma_f32_16x16x32_bf16(af0, bf1, a01, 0, 0, 0);
            a10 = __builtin_amdgcn_mfma_f32_16x16x32_bf16(af1, bf0, a10, 0, 0, 0);
            a11 = __builtin_amdgcn_mfma_f32_16x16x32_bf16(af1, bf1, a11, 0, 0, 0);
        }
        float bia = b1[wave * 32 + l15], bib = b1[wave * 32 + 16 + l15];
#pragma unroll
        for (int j = 0; j < 4; j++) {
            int r0 = l4 * 4 + j;
            Xs[r0 * 136 + wave * 32 + l15]             = (short)f2bf(leaky_f(a00[j] + bia));
            Xs[r0 * 136 + wave * 32 + 16 + l15]        = (short)f2bf(leaky_f(a01[j] + bib));
            Xs[(r0 + 16) * 136 + wave * 32 + l15]      = (short)f2bf(leaky_f(a10[j] + bia));
            Xs[(r0 + 16) * 136 + wave * 32 + 16 + l15] = (short)f2bf(leaky_f(a11[j] + bib));
        }
    }
    __syncthreads();

    // ---- Phase 2: h = leaky(x @ W2^T + b2), K=128 ----
    a00 = f32x4{0.f,0.f,0.f,0.f}; a01 = f32x4{0.f,0.f,0.f,0.f};
    a10 = f32x4{0.f,0.f,0.f,0.f}; a11 = f32x4{0.f,0.f,0.f,0.f};
    const short* xp0 = &Xs[l15 * 136 + l4 * 8];
    const short* xp1 = &Xs[(16 + l15) * 136 + l4 * 8];
    {
        const unsigned short* bp = pw2 + (size_t)(wave * 2) * 512 + lane * 8;
#pragma unroll
        for (int k = 0; k < 4; k++) {
            bf16x8 af0 = *reinterpret_cast<const bf16x8*>(xp0 + k * 32);
            bf16x8 af1 = *reinterpret_cast<const bf16x8*>(xp1 + k * 32);
            bf16x8 bf0 = *reinterpret_cast<const bf16x8*>(bp + (size_t)k * 8 * 512);
            bf16x8 bf1 = *reinterpret_cast<const bf16x8*>(bp + (size_t)k * 8 * 512 + 512);
            a00 = __builtin_amdgcn_mfma_f32_16x16x32_bf16(af0, bf0, a00, 0, 0, 0);
            a01 = __builtin_amdgcn_mfma_f32_16x16x32_bf16(af0, bf1, a01, 0, 0, 0);
            a10 = __builtin_amdgcn_mfma_f32_16x16x32_bf16(af1, bf0, a10, 0, 0, 0);
            a11 = __builtin_amdgcn_mfma_f32_16x16x32_bf16(af1, bf1, a11, 0, 0, 0);
        }
    }
    float hv00[4], hv01[4], hv10[4], hv11[4], pn0[4], pn1[4];
    {
        float bia = b2[wave * 32 + l15], bib = b2[wave * 32 + 16 + l15];
#pragma unroll
        for (int j = 0; j < 4; j++) {
            hv00[j] = leaky_f(a00[j] + bia);
            hv01[j] = leaky_f(a01[j] + bib);
            hv10[j] = leaky_f(a10[j] + bia);
            hv11[j] = leaky_f(a11[j] + bib);
            float s0 = hv00[j] * hv00[j] + hv01[j] * hv01[j];
            s0 += __shfl_xor(s0, 1); s0 += __shfl_xor(s0, 2);
            s0 += __shfl_xor(s0, 4); s0 += __shfl_xor(s0, 8);
            pn0[j] = s0;
            float s1 = hv10[j] * hv10[j] + hv11[j] * hv11[j];
            s1 += __shfl_xor(s1, 1); s1 += __shfl_xor(s1, 2);
            s1 += __shfl_xor(s1, 4); s1 += __shfl_xor(s1, 8);
            pn1[j] = s1;
        }
    }
    __syncthreads();   // all waves done reading Xs(x); h still in registers

#pragma unroll
    for (int j = 0; j < 4; j++) {
        int r0 = l4 * 4 + j;
        Xs[r0 * 136 + wave * 32 + l15]             = (short)f2bf(hv00[j]);
        Xs[r0 * 136 + wave * 32 + 16 + l15]        = (short)f2bf(hv01[j]);
        Xs[(r0 + 16) * 136 + wave * 32 + l15]      = (short)f2bf(hv10[j]);
        Xs[(r0 + 16) * 136 + wave * 32 + 16 + l15] = (short)f2bf(hv11[j]);
        __builtin_nontemporal_store(hv00[j], &h_out[(size_t)(rowBlk + r0) * 128 + wave * 32 + l15]);
        __builtin_nontemporal_store(hv01[j], &h_out[(size_t)(rowBlk + r0) * 128 + wave * 32 + 16 + l15]);
        __builtin_nontemporal_store(hv10[j], &h_out[(size_t)(rowBlk + 16 + r0) * 128 + wave * 32 + l15]);
        __builtin_nontemporal_store(hv11[j], &h_out[(size_t)(rowBlk + 16 + r0) * 128 + wave * 32 + 16 + l15]);
        if (l15 == 0) { hn2s[wave][r0] = pn0[j]; hn2s[wave][16 + r0] = pn1[j]; }
    }
    __syncthreads();   // h ready in Xs

    // ---- Phase 3: [hW | q] = h @ [W21;cent]^T, K=128, 192 cols in 4x48 ----
    f32x4 c00{0.f,0.f,0.f,0.f}, c01{0.f,0.f,0.f,0.f}, c02{0.f,0.f,0.f,0.f};
    f32x4 c10{0.f,0.f,0.f,0.f}, c11{0.f,0.f,0.f,0.f}, c12{0.f,0.f,0.f,0.f};
    {
        const unsigned short* bp = pw3 + (size_t)(wave * 3) * 512 + lane * 8;
#pragma unroll
        for (int k = 0; k < 4; k++) {
            bf16x8 af0 = *reinterpret_cast<const bf16x8*>(xp0 + k * 32);
            bf16x8 af1 = *reinterpret_cast<const bf16x8*>(xp1 + k * 32);
            bf16x8 bf0 = *reinterpret_cast<const bf16x8*>(bp + (size_t)k * 12 * 512);
            bf16x8 bf1 = *reinterpret_cast<const bf16x8*>(bp + (size_t)k * 12 * 512 + 512);
            bf16x8 bf2 = *reinterpret_cast<const bf16x8*>(bp + (size_t)k * 12 * 512 + 1024);
            c00 = __builtin_amdgcn_mfma_f32_16x16x32_bf16(af0, bf0, c00, 0, 0, 0);
            c01 = __builtin_amdgcn_mfma_f32_16x16x32_bf16(af0, bf1, c01, 0, 0, 0);
            c02 = __builtin_amdgcn_mfma_f32_16x16x32_bf16(af0, bf2, c02, 0, 0, 0);
            c10 = __builtin_amdgcn_mfma_f32_16x16x32_bf16(af1, bf0, c10, 0, 0, 0);
            c11 = __builtin_amdgcn_mfma_f32_16x16x32_bf16(af1, bf1, c11, 0, 0, 0);
            c12 = __builtin_amdgcn_mfma_f32_16x16x32_bf16(af1, bf2, c12, 0, 0, 0);
        }
    }
    {
        float hn2r0[4], hn2r1[4];
#pragma unroll
        for (int j = 0; j < 4; j++) {
            int r0 = l4 * 4 + j;
            hn2r0[j] = hn2s[0][r0] + hn2s[1][r0] + hn2s[2][r0] + hn2s[3][r0];
            hn2r1[j] = hn2s[0][16 + r0] + hn2s[1][16 + r0] + hn2s[2][16 + r0] + hn2s[3][16 + r0];
        }
        f32x4 av0[3] = {c00, c01, c02};
        f32x4 av1[3] = {c10, c11, c12};
#pragma unroll
        for (int ff = 0; ff < 3; ff++) {
            int col = wave * 48 + ff * 16 + l15;
            if (col < 128) {
#pragma unroll
                for (int j = 0; j < 4; j++) {
                    int gr0 = rowBlk + l4 * 4 + j;
                    hWb[(size_t)gr0 * 128 + col]        = f2bf(av0[ff][j]);
                    hWb[(size_t)(gr0 + 16) * 128 + col] = f2bf(av1[ff][j]);
                }
            } else {
                int c2 = col - 128;
                float cn2v = cn2g[c2];
#pragma unroll
                for (int j = 0; j < 4; j++) {
                    int gr0 = rowBlk + l4 * 4 + j;
                    float q0 = 1.f / (1.f + cn2v + hn2r0[j] - 2.f * av0[ff][j]);
                    float q1 = 1.f / (1.f + cn2v + hn2r1[j] - 2.f * av1[ff][j]);
                    qtb[(size_t)gr0 * 64 + c2]        = f2bf(q0);
                    qtb[(size_t)(gr0 + 16) * 64 + c2] = f2bf(q1);
                }
            }
        }
    }
}

// ==================== per-node aggregation: one wave per node, barrier-free (R17 best) ====================
struct PerWaveU {
    union {
        unsigned short qs[1024];   // 2 KB: staged q rows [e*64+hc]
        float wbuf[16][16];        // 1 KB: softmax weights [e][c] (after qs consumed)
    };
};

__global__ __launch_bounds__(256)
void agg_kernel(const int* __restrict__ adj, const unsigned short* __restrict__ qtb,
                const unsigned short* __restrict__ hWb, const float* __restrict__ b21,
                const float* __restrict__ headConv, float* __restrict__ out1)
{
    __shared__ __align__(16) unsigned short hs[4][16 * 128];   // 16 KB
    __shared__ __align__(16) PerWaveU upw[4];                  // 8 KB  (total 24 KB)

    const int wv = threadIdx.x >> 6, lane = threadIdx.x & 63;
    const int eg = lane >> 4, l15 = lane & 15;
    const int n = blockIdx.x * 4 + wv;

    const int myadj = adj[n * 16 + l15];

    // stage q (16 rows x 128B) and hW (16 rows x 256B), linear LDS, conflict-free
#pragma unroll
    for (int i = 0; i < 2; i++) {
        int row = i * 8 + (lane >> 3);
        int nb = __shfl(myadj, row);
        *reinterpret_cast<u16x8*>(&upw[wv].qs[i * 512 + lane * 8]) =
            *reinterpret_cast<const u16x8*>(qtb + (size_t)nb * 64 + (lane & 7) * 8);
    }
#pragma unroll
    for (int i = 0; i < 4; i++) {
        int row = i * 4 + eg;
        int nb = __shfl(myadj, row);
        *reinterpret_cast<u16x8*>(&hs[wv][i * 512 + lane * 8]) =
            *reinterpret_cast<const u16x8*>(hWb + (size_t)nb * 128 + l15 * 8);
    }
    // no barrier: wave-private LDS, DS in-order

    // softmax (lane = hc): xor16 via shfl (DS), xor32 via permlane (VALU); no max-subtract
    {
        float qv[16];
        float s = 0.f;
#pragma unroll
        for (int e = 0; e < 16; e++) { qv[e] = bf2f(upw[wv].qs[e * 64 + lane]); s += qv[e]; }
        float rs = 1.f / s;
        float conv = headConv[eg];
        float ex[4] = {0.f, 0.f, 0.f, 0.f};
#pragma unroll
        for (int e = 0; e < 16; e++) {
            float v = conv * qv[e] * rs;
            v += __shfl_xor(v, 16);
            v = xor32_add(v);             // all lanes hold logit[c=l15][e]
            float evv = __expf(v);        // |v| <= 6.2, f32-safe
            bool mine = (eg == (e >> 2));
            ex[e & 3] = mine ? evv : ex[e & 3];
        }
        float ps = ex[0] + ex[1] + ex[2] + ex[3];
        ps += __shfl_xor(ps, 16);
        ps = xor32_add(ps);
        float inv = 1.f / ps;
#pragma unroll
        for (int j = 0; j < 4; j++) upw[wv].wbuf[eg * 4 + j][l15] = ex[j] * inv;
        // no barrier: same-wave overlay; all qs reads above precede these writes
    }

    // PV: lane (cg=eg, dg=l15) covers c = eg*4+jc, d = l15*4..+3 and +64..+67
    {
        const int d0 = l15 * 4;
        float bvf[8];
        *reinterpret_cast<float4*>(bvf)     = *reinterpret_cast<const float4*>(b21 + d0);
        *reinterpret_cast<float4*>(bvf + 4) = *reinterpret_cast<const float4*>(b21 + d0 + 64);
        f32x2 acc2[4][4];
#pragma unroll
        for (int jc = 0; jc < 4; jc++) {
            acc2[jc][0] = f32x2{bvf[0], bvf[1]};
            acc2[jc][1] = f32x2{bvf[2], bvf[3]};
            acc2[jc][2] = f32x2{bvf[4], bvf[5]};
            acc2[jc][3] = f32x2{bvf[6], bvf[7]};
        }

#pragma unroll
        for (int e = 0; e < 16; e++) {
            uint2 wlo = *reinterpret_cast<const uint2*>(&hs[wv][e * 128 + d0]);
            uint2 whi = *reinterpret_cast<const uint2*>(&hs[wv][e * 128 + 64 + d0]);
            float w4[4];
            *reinterpret_cast<float4*>(w4) =
                *reinterpret_cast<const float4*>(&upw[wv].wbuf[e][eg * 4]);  // ds_read_b128
            f32x2 hv2[4];
            hv2[0] = f32x2{bflo(wlo.x), bfhi(wlo.x)};
            hv2[1] = f32x2{bflo(wlo.y), bfhi(wlo.y)};
            hv2[2] = f32x2{bflo(whi.x), bfhi(whi.x)};
            hv2[3] = f32x2{bflo(whi.y), bfhi(whi.y)};
#pragma unroll
            for (int jc = 0; jc < 4; jc++) {
                f32x2 w2 = f32x2{w4[jc], w4[jc]};
#pragma unroll
                for (int q = 0; q < 4; q++)
                    acc2[jc][q] = fma2(w2, hv2[q], acc2[jc][q]);
            }
        }

#pragma unroll
        for (int jc = 0; jc < 4; jc++) {
            f32x4 lo, hi;
            lo[0] = leaky_f(acc2[jc][0][0]); lo[1] = leaky_f(acc2[jc][0][1]);
            lo[2] = leaky_f(acc2[jc][1][0]); lo[3] = leaky_f(acc2[jc][1][1]);
            hi[0] = leaky_f(acc2[jc][2][0]); hi[1] = leaky_f(acc2[jc][2][1]);
            hi[2] = leaky_f(acc2[jc][3][0]); hi[3] = leaky_f(acc2[jc][3][1]);
            float* dst = out1 + ((size_t)(n * 16 + eg * 4 + jc)) * 128;
            __builtin_nontemporal_store(lo, reinterpret_cast<f32x4*>(dst + d0));
            __builtin_nontemporal_store(hi, reinterpret_cast<f32x4*>(dst + d0 + 64));
        }
    }
}

extern "C" void kernel_launch(void* const* d_in, const int* in_sizes, int n_in,
                              void* d_out, int out_size, void* d_ws, size_t ws_size,
                              hipStream_t stream)
{
    const float* x_node   = (const float*)d_in[0];
    const int*   adj      = (const int*)  d_in[1];
    const float* W1       = (const float*)d_in[3];
    const float* b1       = (const float*)d_in[4];
    const float* W2       = (const float*)d_in[5];
    const float* b2       = (const float*)d_in[6];
    const float* W21      = (const float*)d_in[7];
    const float* b21      = (const float*)d_in[8];
    const float* cent     = (const float*)d_in[9];
    const float* headConv = (const float*)d_in[10];

    const int N = in_sizes[0] / 256;     // 20000

    float* h    = (float*)d_out;                 // h_prime [N][128]
    float* out1 = h + (size_t)N * 128;           // new_feat [N][16][128]

    unsigned short* xb  = (unsigned short*)d_ws;       // [N][256] bf16
    unsigned short* hWb = xb  + (size_t)N * 256;       // [N][128] bf16
    unsigned short* qtb = hWb + (size_t)N * 128;       // [N][64]  bf16
    unsigned short* pw1 = qtb + (size_t)N * 64;        // 32768
    unsigned short* pw2 = pw1 + 32768;                 // 16384
    unsigned short* pw3 = pw2 + 16384;                 // 24576
    float*          cn2g = (float*)(pw3 + 24576);      // [64]

    const int xblocks = (N * 256) / 4096;              // 1250

    pack_kernel<<<37 + xblocks, 256, 0, stream>>>(x_node, W1, W2, W21, cent,
                                                  xb, pw1, pw2, pw3, cn2g, N);
    fused_gemms<<<N / 32, 256, 0, stream>>>(xb, pw1, pw2, pw3, b1, b2, cn2g,
                                            h, hWb, qtb, N);
    agg_kernel<<<N / 4, 256, 0, stream>>>(adj, qtb, hWb, b21, headConv, out1);
}